// Round 1
// baseline (278.753 us; speedup 1.0000x reference)
//
#include <hip/hip_runtime.h>
#include <hip/hip_bf16.h>

// CRF broadcast-add: out[b,l,i,j] = emission[b,l,j] + transition[i,j]
// B=32, L=512, T=64, fp32. Output = 67.1M floats (256 MiB) -> write-BW bound.
//
// One thread per float4 (16B) of output:
//   g    : global float4 index in [0, 16,777,216)
//   j4   = g & 15          (j group of 4, fastest dim)
//   i    = (g >> 4) & 63
//   bl   = g >> 10         (fused b*L + l index)
// Stores: 64 lanes x 16B contiguous = fully coalesced.
// Loads: emission row (64 floats) reused 64x per (b,l) -> L2-served;
//        transition (16 KiB) fully L1-resident.

__global__ __launch_bounds__(256) void crf_scores_kernel(
    const float* __restrict__ emission,   // [B*L, T]  (float4 view: [B*L, 16])
    const float* __restrict__ transition, // [T, T]    (float4 view: [64, 16])
    float* __restrict__ out)              // [B*L, T, T] (float4 view: [.., 64, 16])
{
    const float4* __restrict__ em4 = reinterpret_cast<const float4*>(emission);
    const float4* __restrict__ tr4 = reinterpret_cast<const float4*>(transition);
    float4* __restrict__ out4 = reinterpret_cast<float4*>(out);

    unsigned int g = blockIdx.x * blockDim.x + threadIdx.x; // < 16,777,216

    unsigned int j4 = g & 15u;
    unsigned int i  = (g >> 4) & 63u;
    unsigned int bl = g >> 10;

    float4 e = em4[(bl << 4) | j4];
    float4 t = tr4[(i << 4) | j4];

    float4 r;
    r.x = e.x + t.x;
    r.y = e.y + t.y;
    r.z = e.z + t.z;
    r.w = e.w + t.w;

    out4[g] = r;
}

extern "C" void kernel_launch(void* const* d_in, const int* in_sizes, int n_in,
                              void* d_out, int out_size, void* d_ws, size_t ws_size,
                              hipStream_t stream) {
    const float* emission   = (const float*)d_in[0]; // [32, 512, 64]
    const float* transition = (const float*)d_in[1]; // [64, 64]
    float* out = (float*)d_out;                      // [32, 512, 64, 64]

    // total float4 elements = 32*512*64*64 / 4 = 16,777,216
    const unsigned int n4 = 16u * 1024u * 1024u;
    const int block = 256;
    const int grid = (int)(n4 / block); // 65536 blocks

    crf_scores_kernel<<<grid, block, 0, stream>>>(emission, transition, out);
}

// Round 3
// 264.083 us; speedup vs baseline: 1.0556x; 1.0556x over previous
//
#include <hip/hip_runtime.h>
#include <hip/hip_bf16.h>

// CRF broadcast-add: out[b,l,i,j] = emission[b,l,j] + transition[i,j]
// B=32, L=512, T=64, fp32. Output = 256 MiB -> pure write-BW bound.
// Roofline: (256 MiB store + 4 MiB load) / 6.5 TB/s ~= 42 us.
//
// v3 = v2 with native clang vector type for the nontemporal builtin
// (HIP_vector_type float4 is a class -> builtin rejects it; an
// ext_vector_type(4) float lowers to the same global_store_dwordx4 + nt).

typedef float v4f __attribute__((ext_vector_type(4)));

__global__ __launch_bounds__(256) void crf_scores_kernel(
    const float* __restrict__ emission,   // [B*L, T]  (v4f view: [B*L, 16])
    const float* __restrict__ transition, // [T, T]    (v4f view: [64, 16])
    float* __restrict__ out)              // [B*L, T, T] (v4f view)
{
    const v4f* __restrict__ em4 = reinterpret_cast<const v4f*>(emission);
    const v4f* __restrict__ tr4 = reinterpret_cast<const v4f*>(transition);
    v4f* __restrict__ out4 = reinterpret_cast<v4f*>(out);

    const unsigned int stride = 4u * 1024u * 1024u;  // total threads = n4/4
    unsigned int t = blockIdx.x * blockDim.x + threadIdx.x;

#pragma unroll
    for (int k = 0; k < 4; ++k) {
        unsigned int g = t + (unsigned int)k * stride; // float4 index < 16M

        unsigned int j4 = g & 15u;
        unsigned int i  = (g >> 4) & 63u;
        unsigned int bl = g >> 10;

        v4f e  = em4[(bl << 4) | j4];
        v4f tv = tr4[(i << 4) | j4];
        v4f r  = e + tv;

        __builtin_nontemporal_store(r, &out4[g]);
    }
}

extern "C" void kernel_launch(void* const* d_in, const int* in_sizes, int n_in,
                              void* d_out, int out_size, void* d_ws, size_t ws_size,
                              hipStream_t stream) {
    const float* emission   = (const float*)d_in[0]; // [32, 512, 64]
    const float* transition = (const float*)d_in[1]; // [64, 64]
    float* out = (float*)d_out;                      // [32, 512, 64, 64]

    // total float4 = 16,777,216; 4 per thread -> 4,194,304 threads
    const int block = 256;
    const int grid = 16384;

    crf_scores_kernel<<<grid, block, 0, stream>>>(emission, transition, out);
}